// Round 7
// baseline (541.792 us; speedup 1.0000x reference)
//
#include <hip/hip_runtime.h>
#include <hip/hip_bf16.h>

typedef __attribute__((ext_vector_type(8))) short short8;
typedef __attribute__((ext_vector_type(4))) float floatx4;

#define NSEQ 16
#define SEQ 128
#define DIM 256
#define HID 256
#define K3H 768
#define K2D 512
#define LOG2E 1.442695041f
#define LOG2E2 2.885390082f
#define WS_STRIDE 772   // 768 + 4: breaks 16-way preload bank conflict to 2-way (free)

__device__ __forceinline__ float frcp(float x) { return __builtin_amdgcn_rcpf(x); }
__device__ __forceinline__ float ftanh(float x) {
    return 1.f - 2.f * frcp(1.f + __expf(2.f * x));
}
__device__ __forceinline__ unsigned short bf16bits(float v) {
    unsigned u = __builtin_bit_cast(unsigned, v);
    unsigned r = (u + 0x7FFFu + ((u >> 16) & 1u)) >> 16;
    return (unsigned short)r;
}
// async global->LDS DMA, 16B/lane: LDS dest = uniform base + lane*16 (HW rule)
__device__ __forceinline__ void load_lds16(const float* gsrc, float* ldsbase) {
    __builtin_amdgcn_global_load_lds(
        (const __attribute__((address_space(1))) void*)gsrc,
        (__attribute__((address_space(3))) void*)ldsbase, 16, 0, 0);
}

// ---------------- K1: left = x@w1, right = x@w2  (8 rows/block, v1-proven) ----------------
__global__ __launch_bounds__(256) void k1_leftright(
        const float* __restrict__ x, const float* __restrict__ w1,
        const float* __restrict__ w2, float* __restrict__ left,
        float* __restrict__ right) {
    __shared__ __align__(16) float xs[8][DIM];
    const int tid = threadIdx.x;
    const int r0 = blockIdx.x * 8;
    #pragma unroll
    for (int i = 0; i < 8; ++i) xs[i][tid] = x[(r0 + i) * DIM + tid];
    __syncthreads();
    float accL[8], accR[8];
    #pragma unroll
    for (int i = 0; i < 8; ++i) { accL[i] = 0.f; accR[i] = 0.f; }
    #pragma unroll 4
    for (int d = 0; d < DIM; ++d) {
        float wa = w1[d * DIM + tid];
        float wb = w2[d * DIM + tid];
        #pragma unroll
        for (int i = 0; i < 8; ++i) {
            float xv = xs[i][d];
            accL[i] = fmaf(xv, wa, accL[i]);
            accR[i] = fmaf(xv, wb, accR[i]);
        }
    }
    #pragma unroll
    for (int i = 0; i < 8; ++i) {
        left[(r0 + i) * DIM + tid]  = accL[i];
        right[(r0 + i) * DIM + tid] = accR[i];
    }
}

// ---------------- K2: scores (tanh, v3 dot), softmax, c = score@x ----------------
__global__ __launch_bounds__(128) void k2_attn(
        const float* __restrict__ x, const float* __restrict__ left,
        const float* __restrict__ right, const float* __restrict__ bias,
        const float* __restrict__ v3, float* __restrict__ cout) {
    __shared__ __align__(16) float lm[DIM];
    __shared__ __align__(16) float v3s[DIM];
    __shared__ float p[SEQ];
    __shared__ float red[2];
    const int tid = threadIdx.x;      // 0..127 (= n)
    const int lane = tid & 63;
    const int wid = tid >> 6;         // 0..1
    const int bm = blockIdx.x;        // 0..2047
    const int b = bm >> 7;            // sequence index

    const float* lrow = left + bm * DIM;
    #pragma unroll
    for (int q = 0; q < 2; ++q) {
        int d = tid + q * 128;
        lm[d]  = lrow[d] + bias[d];
        v3s[d] = v3[d];
    }
    __syncthreads();

    const float4* rrow = reinterpret_cast<const float4*>(right + (b * SEQ + tid) * DIM);
    const float4* lm4  = reinterpret_cast<const float4*>(lm);
    const float4* vv4  = reinterpret_cast<const float4*>(v3s);
    float s = 0.f;
    for (int d4 = 0; d4 < DIM / 4; ++d4) {
        float4 rv = rrow[d4];
        float4 lv = lm4[d4];
        float4 vv = vv4[d4];
        s = fmaf(ftanh(lv.x + rv.x), vv.x, s);
        s = fmaf(ftanh(lv.y + rv.y), vv.y, s);
        s = fmaf(ftanh(lv.z + rv.z), vv.z, s);
        s = fmaf(ftanh(lv.w + rv.w), vv.w, s);
    }
    float m = s;
    #pragma unroll
    for (int off = 32; off >= 1; off >>= 1) m = fmaxf(m, __shfl_xor(m, off, 64));
    if (lane == 0) red[wid] = m;
    __syncthreads();
    m = fmaxf(red[0], red[1]);
    float e = __expf(s - m);
    float t = e;
    #pragma unroll
    for (int off = 32; off >= 1; off >>= 1) t += __shfl_xor(t, off, 64);
    __syncthreads();
    if (lane == 0) red[wid] = t;
    __syncthreads();
    float denom = red[0] + red[1];
    p[tid] = e * frcp(denom);
    __syncthreads();

    const float* xb = x + b * SEQ * DIM;
    float c0 = 0.f, c1 = 0.f;
    #pragma unroll 4
    for (int n = 0; n < SEQ; ++n) {
        float pn = p[n];
        c0 = fmaf(pn, xb[n * DIM + tid], c0);
        c1 = fmaf(pn, xb[n * DIM + tid + 128], c1);
    }
    cout[bm * DIM + tid]       = c0;
    cout[bm * DIM + tid + 128] = c1;
}

// ---------------- K3: xp = [x, c] @ gru_kernel + b_in  (8 rows/block) ----------------
// z/r outputs prescaled by log2e, h by 2*log2e (validated r4/r5).
__global__ __launch_bounds__(256) void k3_xproj(
        const float* __restrict__ x, const float* __restrict__ c,
        const float* __restrict__ gk, const float* __restrict__ gbias,
        float* __restrict__ xp) {
    __shared__ __align__(16) float xc[8][K2D];
    const int tid = threadIdx.x;
    const int r0 = blockIdx.x * 8;
    #pragma unroll
    for (int i = 0; i < 8; ++i) {
        xc[i][tid]       = x[(r0 + i) * DIM + tid];
        xc[i][tid + 256] = c[(r0 + i) * DIM + tid];
    }
    __syncthreads();
    float acc[8][3];
    #pragma unroll
    for (int i = 0; i < 8; ++i) {
        acc[i][0] = gbias[tid];
        acc[i][1] = gbias[256 + tid];
        acc[i][2] = gbias[512 + tid];
    }
    #pragma unroll 2
    for (int k = 0; k < K2D; ++k) {
        float g0 = gk[k * K3H + tid];
        float g1 = gk[k * K3H + 256 + tid];
        float g2 = gk[k * K3H + 512 + tid];
        #pragma unroll
        for (int i = 0; i < 8; ++i) {
            float xv = xc[i][k];
            acc[i][0] = fmaf(xv, g0, acc[i][0]);
            acc[i][1] = fmaf(xv, g1, acc[i][1]);
            acc[i][2] = fmaf(xv, g2, acc[i][2]);
        }
    }
    #pragma unroll
    for (int i = 0; i < 8; ++i) {
        xp[(r0 + i) * K3H + tid]       = acc[i][0] * LOG2E;
        xp[(r0 + i) * K3H + 256 + tid] = acc[i][1] * LOG2E;
        xp[(r0 + i) * K3H + 512 + tid] = acc[i][2] * LOG2E2;
    }
}

// ---------------- K4: GRU recurrence v7 = v6 DMA machinery + v2 in-register gates ----------------
// 16 blocks (1 seq), 512 threads (8 waves). Wave wv owns cols {32wv..32wv+31} of
// EACH gate: tile u -> col = (u>>1)*256 + (u&1)*16 + 32wv + l15. Gate lane (lane<16)
// reads rz/rr/rh straight from C[u][0] — NO rp LDS round-trip, ONE barrier/step.
//  - xq gate inputs: global_load_lds DMA, distance 2, triple-buffered (v6-proven)
//  - A-frags: exec-masked ds_read into pre-zeroed persistent regs (v6-proven)
//  - hbf double-buffered: read cb / write nb, so the single barrier is race-free
//  - barrier = s_waitcnt vmcnt(5) lgkmcnt(0); s_barrier  (5 = st,st,DMA,st,st issued
//    after the DMA being consumed next step; loads stay in flight across barriers)
//  - bias folded into C-init; log2e/2log2e prescale (validated r4/r5)
__global__ __launch_bounds__(512) void k4_gru(
        const float* __restrict__ rec, const float* __restrict__ gbias,
        const float* __restrict__ xp, float* __restrict__ out) {
    __shared__ __align__(16) float ws[16 * WS_STRIDE];    // 49.4KB preload staging
    __shared__ __align__(16) float xq[3][K3H];            // 9KB triple-buffered gate inputs
    __shared__ __align__(16) unsigned short hbf[2][HID];  // 1KB dbuf h (bf16)
    const int tid  = threadIdx.x;
    const int lane = tid & 63;
    const int wv   = tid >> 6;     // 0..7
    const int seq  = blockIdx.x;   // 0..15
    const int l15  = lane & 15;
    const int g4   = lane >> 4;    // 0..3

    // ---- Preload rec_kernel as prescaled bf16 B-fragments (v2 col mapping) ----
    short8 Bf[6][8];
    #pragma unroll
    for (int part = 0; part < 16; ++part) {
        #pragma unroll
        for (int q = 0; q < 6; ++q) {
            int fi = q * 512 + tid;            // 3072 float4 = 16 rows x 192 float4
            int row = fi / 192, c4 = fi % 192;
            reinterpret_cast<float4*>(ws)[row * (WS_STRIDE / 4) + c4] =
                reinterpret_cast<const float4*>(rec + part * 16 * K3H)[fi];
        }
        __syncthreads();
        const int kc = part >> 1, half = part & 1;
        #pragma unroll
        for (int u = 0; u < 6; ++u) {
            const float sc = (u >= 4) ? LOG2E2 : LOG2E;
            const int col = (u >> 1) * 256 + (u & 1) * 16 + wv * 32 + l15;
            #pragma unroll
            for (int j = 0; j < 8; ++j) {
                int r = g4 * 8 + j;            // k within 32-chunk
                if ((r >> 4) == half)
                    Bf[u][kc][j] = (short)bf16bits(ws[(r & 15) * WS_STRIDE + col] * sc);
            }
        }
        __syncthreads();
    }

    // per-lane bias fold (C-init); only row 0 (reg 0, lanes<16) is consumed
    floatx4 br4[6];
    #pragma unroll
    for (int u = 0; u < 6; ++u) {
        const float sc = (u >= 4) ? LOG2E2 : LOG2E;
        const float b = gbias[K3H + (u >> 1) * 256 + (u & 1) * 16 + wv * 32 + l15] * sc;
        br4[u] = (floatx4){b, 0.f, 0.f, 0.f};
    }

    const int d0 = wv * 32 + l15;   // gate lane's t=0 column
    const int d1 = d0 + 16;         // t=1 column
    const float* xps = xp + (size_t)seq * SEQ * K3H;
    float* outs = out + (size_t)seq * SEQ * HID;

    float h0 = 0.f, h1 = 0.f;       // gate lanes' h state
    if (tid < HID) hbf[0][tid] = 0;

    // prologue: DMA rows 0 and 1 into xq[0], xq[1]; full drain once
    if (wv < 3) {
        load_lds16(xps + wv * 256 + (lane << 2),       &xq[0][wv * 256]);
        load_lds16(xps + K3H + wv * 256 + (lane << 2), &xq[1][wv * 256]);
    }
    asm volatile("s_waitcnt vmcnt(0)" ::: "memory");
    __syncthreads();

    // persistent pre-zeroed A-fragments (only l15==0 lanes ever written)
    short8 av[8];
    #pragma unroll
    for (int kc = 0; kc < 8; ++kc) av[kc] = (short8){0, 0, 0, 0, 0, 0, 0, 0};

    int bc = 0, bn2 = 2;            // xq buffer for step s, and for s+2
    for (int s = 0; s < SEQ; ++s) {
        const int cb = s & 1, nb = cb ^ 1;

        // (A) DMA prefetch row s+2 (waves 0-2; no VGPR round-trip)
        if (wv < 3 && s + 2 < SEQ)
            load_lds16(xps + (s + 2) * K3H + wv * 256 + (lane << 2), &xq[bn2][wv * 256]);

        // (B) A-fragments: exec-masked reads from hbf[cb], conflict-free banks
        if (l15 == 0) {
            #pragma unroll
            for (int kc = 0; kc < 8; ++kc)
                av[kc] = *reinterpret_cast<const short8*>(&hbf[cb][kc * 32 + g4 * 8]);
        }
        // (C) gate inputs from LDS (issued early, consumed after MFMAs)
        float xz0, xz1, xr0, xr1, xh0, xh1;
        if (lane < 16) {
            const float* xc = xq[bc];
            xz0 = xc[d0];       xz1 = xc[d1];
            xr0 = xc[256 + d0]; xr1 = xc[256 + d1];
            xh0 = xc[512 + d0]; xh1 = xc[512 + d1];
        }
        // (D) rp = h @ rec (M=1), bias pre-folded into C
        floatx4 C[6];
        #pragma unroll
        for (int u = 0; u < 6; ++u) C[u] = br4[u];
        #pragma unroll
        for (int kc = 0; kc < 8; ++kc) {
            #pragma unroll
            for (int u = 0; u < 6; ++u)
                C[u] = __builtin_amdgcn_mfma_f32_16x16x32_bf16(av[kc], Bf[u][kc], C[u], 0, 0, 0);
        }
        // (E) gates straight from C (lanes 0-15 of every wave own d0, d1)
        if (lane < 16) {
            float tz0 = C[0][0] + xz0, tz1 = C[1][0] + xz1;
            float tr0 = C[2][0] + xr0, tr1 = C[3][0] + xr1;
            float z0 = frcp(1.f + __builtin_amdgcn_exp2f(-tz0));
            float z1 = frcp(1.f + __builtin_amdgcn_exp2f(-tz1));
            float r0 = frcp(1.f + __builtin_amdgcn_exp2f(-tr0));
            float r1 = frcp(1.f + __builtin_amdgcn_exp2f(-tr1));
            float th0 = fmaf(r0, C[4][0], xh0);
            float th1 = fmaf(r1, C[5][0], xh1);
            float hh0 = 1.f - 2.f * frcp(1.f + __builtin_amdgcn_exp2f(th0));
            float hh1 = 1.f - 2.f * frcp(1.f + __builtin_amdgcn_exp2f(th1));
            h0 = hh0 + z0 * (h0 - hh0);
            h1 = hh1 + z1 * (h1 - hh1);
            outs[s * HID + d0] = h0;
            outs[s * HID + d1] = h1;
            hbf[nb][d0] = bf16bits(h0);
            hbf[nb][d1] = bf16bits(h1);
        }
        // single barrier: LDS drained; DMA loads/out stores stay in flight (vmcnt
        // counted: the DMA consumed next step has exactly 5 newer vm ops)
        asm volatile("s_waitcnt vmcnt(5) lgkmcnt(0)\n\ts_barrier" ::: "memory");

        bc  = (bc == 2)  ? 0 : bc + 1;
        bn2 = (bn2 == 2) ? 0 : bn2 + 1;
    }
}

extern "C" void kernel_launch(void* const* d_in, const int* in_sizes, int n_in,
                              void* d_out, int out_size, void* d_ws, size_t ws_size,
                              hipStream_t stream) {
    const float* feat = (const float*)d_in[0];
    const float* w1   = (const float*)d_in[1];
    const float* w2   = (const float*)d_in[2];
    const float* bias = (const float*)d_in[3];
    const float* v3   = (const float*)d_in[4];
    const float* gk   = (const float*)d_in[5];
    const float* grk  = (const float*)d_in[6];
    const float* gb   = (const float*)d_in[7];
    float* out = (float*)d_out;

    char* wsb = (char*)d_ws;
    float* left  = (float*)(wsb);
    float* right = (float*)(wsb + (size_t)2 * 1024 * 1024);
    float* cbuf  = (float*)(wsb + (size_t)4 * 1024 * 1024);
    float* xp    = (float*)(wsb + (size_t)6 * 1024 * 1024);

    k1_leftright<<<2048 / 8, 256, 0, stream>>>(feat, w1, w2, left, right);
    k2_attn<<<NSEQ * SEQ, 128, 0, stream>>>(feat, left, right, bias, v3, cbuf);
    k3_xproj<<<2048 / 8, 256, 0, stream>>>(feat, cbuf, gk, gb, xp);
    k4_gru<<<NSEQ, 512, 0, stream>>>(grk, gb, xp, out);
}

// Round 8
// 320.990 us; speedup vs baseline: 1.6879x; 1.6879x over previous
//
#include <hip/hip_runtime.h>
#include <hip/hip_bf16.h>

typedef __attribute__((ext_vector_type(8))) short short8;
typedef __attribute__((ext_vector_type(4))) float floatx4;

#define NSEQ 16
#define SEQ 128
#define DIM 256
#define HID 256
#define K3H 768
#define K2D 512
#define LOG2E 1.442695041f
#define LOG2E2 2.885390082f
#define WS_STRIDE 772   // 768 + 4: breaks 16-way preload bank conflict to 2-way (free)

__device__ __forceinline__ float frcp(float x) { return __builtin_amdgcn_rcpf(x); }
__device__ __forceinline__ float ftanh(float x) {
    return 1.f - 2.f * frcp(1.f + __expf(2.f * x));
}
__device__ __forceinline__ unsigned short bf16bits(float v) {
    unsigned u = __builtin_bit_cast(unsigned, v);
    unsigned r = (u + 0x7FFFu + ((u >> 16) & 1u)) >> 16;
    return (unsigned short)r;
}
// async global->LDS DMA, 16B/lane: LDS dest = uniform base + lane*16 (HW rule)
__device__ __forceinline__ void load_lds16(const float* gsrc, float* ldsbase) {
    __builtin_amdgcn_global_load_lds(
        (const __attribute__((address_space(1))) void*)gsrc,
        (__attribute__((address_space(3))) void*)ldsbase, 16, 0, 0);
}

// ---------------- K1: left = x@w1, right = x@w2  (8 rows/block, v1-proven) ----------------
__global__ __launch_bounds__(256) void k1_leftright(
        const float* __restrict__ x, const float* __restrict__ w1,
        const float* __restrict__ w2, float* __restrict__ left,
        float* __restrict__ right) {
    __shared__ __align__(16) float xs[8][DIM];
    const int tid = threadIdx.x;
    const int r0 = blockIdx.x * 8;
    #pragma unroll
    for (int i = 0; i < 8; ++i) xs[i][tid] = x[(r0 + i) * DIM + tid];
    __syncthreads();
    float accL[8], accR[8];
    #pragma unroll
    for (int i = 0; i < 8; ++i) { accL[i] = 0.f; accR[i] = 0.f; }
    #pragma unroll 4
    for (int d = 0; d < DIM; ++d) {
        float wa = w1[d * DIM + tid];
        float wb = w2[d * DIM + tid];
        #pragma unroll
        for (int i = 0; i < 8; ++i) {
            float xv = xs[i][d];
            accL[i] = fmaf(xv, wa, accL[i]);
            accR[i] = fmaf(xv, wb, accR[i]);
        }
    }
    #pragma unroll
    for (int i = 0; i < 8; ++i) {
        left[(r0 + i) * DIM + tid]  = accL[i];
        right[(r0 + i) * DIM + tid] = accR[i];
    }
}

// ---------------- K2: scores (tanh, v3 dot), softmax, c = score@x ----------------
__global__ __launch_bounds__(128) void k2_attn(
        const float* __restrict__ x, const float* __restrict__ left,
        const float* __restrict__ right, const float* __restrict__ bias,
        const float* __restrict__ v3, float* __restrict__ cout) {
    __shared__ __align__(16) float lm[DIM];
    __shared__ __align__(16) float v3s[DIM];
    __shared__ float p[SEQ];
    __shared__ float red[2];
    const int tid = threadIdx.x;      // 0..127 (= n)
    const int lane = tid & 63;
    const int wid = tid >> 6;         // 0..1
    const int bm = blockIdx.x;        // 0..2047
    const int b = bm >> 7;            // sequence index

    const float* lrow = left + bm * DIM;
    #pragma unroll
    for (int q = 0; q < 2; ++q) {
        int d = tid + q * 128;
        lm[d]  = lrow[d] + bias[d];
        v3s[d] = v3[d];
    }
    __syncthreads();

    const float4* rrow = reinterpret_cast<const float4*>(right + (b * SEQ + tid) * DIM);
    const float4* lm4  = reinterpret_cast<const float4*>(lm);
    const float4* vv4  = reinterpret_cast<const float4*>(v3s);
    float s = 0.f;
    for (int d4 = 0; d4 < DIM / 4; ++d4) {
        float4 rv = rrow[d4];
        float4 lv = lm4[d4];
        float4 vv = vv4[d4];
        s = fmaf(ftanh(lv.x + rv.x), vv.x, s);
        s = fmaf(ftanh(lv.y + rv.y), vv.y, s);
        s = fmaf(ftanh(lv.z + rv.z), vv.z, s);
        s = fmaf(ftanh(lv.w + rv.w), vv.w, s);
    }
    float m = s;
    #pragma unroll
    for (int off = 32; off >= 1; off >>= 1) m = fmaxf(m, __shfl_xor(m, off, 64));
    if (lane == 0) red[wid] = m;
    __syncthreads();
    m = fmaxf(red[0], red[1]);
    float e = __expf(s - m);
    float t = e;
    #pragma unroll
    for (int off = 32; off >= 1; off >>= 1) t += __shfl_xor(t, off, 64);
    __syncthreads();
    if (lane == 0) red[wid] = t;
    __syncthreads();
    float denom = red[0] + red[1];
    p[tid] = e * frcp(denom);
    __syncthreads();

    const float* xb = x + b * SEQ * DIM;
    float c0 = 0.f, c1 = 0.f;
    #pragma unroll 4
    for (int n = 0; n < SEQ; ++n) {
        float pn = p[n];
        c0 = fmaf(pn, xb[n * DIM + tid], c0);
        c1 = fmaf(pn, xb[n * DIM + tid + 128], c1);
    }
    cout[bm * DIM + tid]       = c0;
    cout[bm * DIM + tid + 128] = c1;
}

// ---------------- K3: xp = [x,c]@gru_kernel + b_in + b_rec, prescaled ----------------
// b_rec folded here (k4's recurrent matvec then needs NO bias at all); z/r
// prescaled by log2e, h by 2*log2e (validated r4/r5).
__global__ __launch_bounds__(256) void k3_xproj(
        const float* __restrict__ x, const float* __restrict__ c,
        const float* __restrict__ gk, const float* __restrict__ gbias,
        float* __restrict__ xp) {
    __shared__ __align__(16) float xc[8][K2D];
    const int tid = threadIdx.x;
    const int r0 = blockIdx.x * 8;
    #pragma unroll
    for (int i = 0; i < 8; ++i) {
        xc[i][tid]       = x[(r0 + i) * DIM + tid];
        xc[i][tid + 256] = c[(r0 + i) * DIM + tid];
    }
    __syncthreads();
    const float bz = gbias[tid]       + gbias[K3H + tid];        // b_in + b_rec
    const float brr = gbias[256 + tid] + gbias[K3H + 256 + tid];
    const float bh = gbias[512 + tid];                            // b_rec_h NOT added:
    const float bhr = gbias[K3H + 512 + tid];                     // rh term keeps own bias
    float acc[8][3];
    #pragma unroll
    for (int i = 0; i < 8; ++i) {
        acc[i][0] = bz;
        acc[i][1] = brr;
        acc[i][2] = bh;
    }
    #pragma unroll 2
    for (int k = 0; k < K2D; ++k) {
        float g0 = gk[k * K3H + tid];
        float g1 = gk[k * K3H + 256 + tid];
        float g2 = gk[k * K3H + 512 + tid];
        #pragma unroll
        for (int i = 0; i < 8; ++i) {
            float xv = xc[i][k];
            acc[i][0] = fmaf(xv, g0, acc[i][0]);
            acc[i][1] = fmaf(xv, g1, acc[i][1]);
            acc[i][2] = fmaf(xv, g2, acc[i][2]);
        }
    }
    // NOTE: hh = tanh(xh + r*(rh + b_rec_h)) — b_rec_h multiplies r, so it can't
    // fold into xh. k4 adds it via the C-init of the h-tiles instead? No regs for
    // that — so we keep b_rec_h in xp's 4th... simplest correct option: write the
    // h-gate xp WITHOUT b_rec_h and pass b_rec_h via a tiny side buffer? To stay
    // zero-extra-state in k4, we instead fold b_rec_h into the MFMA by appending
    // it as a virtual K-row: h_bf always has a trailing 1.0 row? That changes K.
    // => Decision: keep b_rec_h inside xp as separate stream is wrong; instead we
    // keep it folded into the weights' C-init in k4 via LDS (1 ds_read/step).
    // Here we just emit the three gates prescaled; b_rec_h goes to xp4 below.
    #pragma unroll
    for (int i = 0; i < 8; ++i) {
        xp[(r0 + i) * K3H + tid]       = acc[i][0] * LOG2E;
        xp[(r0 + i) * K3H + 256 + tid] = acc[i][1] * LOG2E;
        xp[(r0 + i) * K3H + 512 + tid] = acc[i][2] * LOG2E2;
    }
}

// ---------------- K4: GRU recurrence v8 = v7 structure + register diet ----------------
// Changes vs v7 (single barrier, in-register gates, DMA dist-2 all kept):
//  (1) no bias regs: b_rec(z,r) folded into xp by k3; b_rec_h read from LDS (brh_l)
//      once per step (2 scalars per gate lane), C-init = 0.
//  (2) A-frags: UNMASKED broadcast ds_read per kc inside the MFMA loop (all 16
//      row-lanes read the same h fragment -> A rows all equal h; only C row 0 is
//      consumed; h finite so no NaN). Kills 32 persistent regs + all exec masking.
//  (3) xq gate-input LDS reads moved AFTER the MFMA block (no live-across).
// Register demand ~250 <= 256 cap (2 waves/SIMD) -> no scratch spill.
__global__ __launch_bounds__(512) void k4_gru(
        const float* __restrict__ rec, const float* __restrict__ gbias,
        const float* __restrict__ xp, float* __restrict__ out) {
    __shared__ __align__(16) float ws[16 * WS_STRIDE];    // 49.4KB preload staging
    __shared__ __align__(16) float xq[3][K3H];            // 9KB triple-buffered gate inputs
    __shared__ __align__(16) unsigned short hbf[2][HID];  // 1KB dbuf h (bf16)
    __shared__ __align__(16) float brh[HID];              // b_rec_h * 2log2e
    const int tid  = threadIdx.x;
    const int lane = tid & 63;
    const int wv   = tid >> 6;     // 0..7
    const int seq  = blockIdx.x;   // 0..15
    const int l15  = lane & 15;
    const int g4   = lane >> 4;    // 0..3

    // ---- Preload rec_kernel as prescaled bf16 B-fragments (v2/v7 col mapping) ----
    short8 Bf[6][8];
    #pragma unroll
    for (int part = 0; part < 16; ++part) {
        #pragma unroll
        for (int q = 0; q < 6; ++q) {
            int fi = q * 512 + tid;            // 3072 float4 = 16 rows x 192 float4
            int row = fi / 192, c4 = fi % 192;
            reinterpret_cast<float4*>(ws)[row * (WS_STRIDE / 4) + c4] =
                reinterpret_cast<const float4*>(rec + part * 16 * K3H)[fi];
        }
        __syncthreads();
        const int kc = part >> 1, half = part & 1;
        #pragma unroll
        for (int u = 0; u < 6; ++u) {
            const float sc = (u >= 4) ? LOG2E2 : LOG2E;
            const int col = (u >> 1) * 256 + (u & 1) * 16 + wv * 32 + l15;
            #pragma unroll
            for (int j = 0; j < 8; ++j) {
                int r = g4 * 8 + j;            // k within 32-chunk
                if ((r >> 4) == half)
                    Bf[u][kc][j] = (short)bf16bits(ws[(r & 15) * WS_STRIDE + col] * sc);
            }
        }
        __syncthreads();
    }

    if (tid < HID) brh[tid] = gbias[K3H + 512 + tid] * LOG2E2;

    const int d0 = wv * 32 + l15;   // gate lane's t=0 column
    const int d1 = d0 + 16;         // t=1 column
    const float* xps = xp + (size_t)seq * SEQ * K3H;
    float* outs = out + (size_t)seq * SEQ * HID;

    float h0 = 0.f, h1 = 0.f;       // gate lanes' h state
    if (tid < HID) hbf[0][tid] = 0;

    // prologue: DMA rows 0 and 1 into xq[0], xq[1]; full drain once
    if (wv < 3) {
        load_lds16(xps + wv * 256 + (lane << 2),       &xq[0][wv * 256]);
        load_lds16(xps + K3H + wv * 256 + (lane << 2), &xq[1][wv * 256]);
    }
    asm volatile("s_waitcnt vmcnt(0)" ::: "memory");
    __syncthreads();

    int bc = 0, bn2 = 2;            // xq buffer for step s, and for s+2
    for (int s = 0; s < SEQ; ++s) {
        const int cb = s & 1, nb = cb ^ 1;

        // (A) DMA prefetch row s+2 (waves 0-2; no VGPR round-trip)
        if (wv < 3 && s + 2 < SEQ)
            load_lds16(xps + (s + 2) * K3H + wv * 256 + (lane << 2), &xq[bn2][wv * 256]);

        // (B) rp = h @ rec (M=1, A rows broadcast-equal), C init = 0 (biases folded)
        floatx4 C[6];
        #pragma unroll
        for (int u = 0; u < 6; ++u) C[u] = (floatx4){0.f, 0.f, 0.f, 0.f};
        #pragma unroll
        for (int kc = 0; kc < 8; ++kc) {
            // unmasked broadcast: every 16-lane group reads the same 16B of h
            short8 a = *reinterpret_cast<const short8*>(&hbf[cb][kc * 32 + g4 * 8]);
            #pragma unroll
            for (int u = 0; u < 6; ++u)
                C[u] = __builtin_amdgcn_mfma_f32_16x16x32_bf16(a, Bf[u][kc], C[u], 0, 0, 0);
        }
        // (C) gates straight from C (lanes 0-15 of every wave own d0, d1);
        //     xq reads AFTER the MFMA block so they don't live across it
        if (lane < 16) {
            const float* xc = xq[bc];
            float tz0 = C[0][0] + xc[d0];
            float tz1 = C[1][0] + xc[d1];
            float tr0 = C[2][0] + xc[256 + d0];
            float tr1 = C[3][0] + xc[256 + d1];
            float z0 = frcp(1.f + __builtin_amdgcn_exp2f(-tz0));
            float z1 = frcp(1.f + __builtin_amdgcn_exp2f(-tz1));
            float r0 = frcp(1.f + __builtin_amdgcn_exp2f(-tr0));
            float r1 = frcp(1.f + __builtin_amdgcn_exp2f(-tr1));
            float th0 = fmaf(r0, C[4][0] + brh[d0], xc[512 + d0]);
            float th1 = fmaf(r1, C[5][0] + brh[d1], xc[512 + d1]);
            float hh0 = 1.f - 2.f * frcp(1.f + __builtin_amdgcn_exp2f(th0));
            float hh1 = 1.f - 2.f * frcp(1.f + __builtin_amdgcn_exp2f(th1));
            h0 = hh0 + z0 * (h0 - hh0);
            h1 = hh1 + z1 * (h1 - hh1);
            outs[s * HID + d0] = h0;
            outs[s * HID + d1] = h1;
            hbf[nb][d0] = bf16bits(h0);
            hbf[nb][d1] = bf16bits(h1);
        }
        // single barrier: LDS drained; DMA loads/out stores stay in flight
        // (vmcnt counted: DMA consumed next step has exactly 5 newer vm ops)
        asm volatile("s_waitcnt vmcnt(5) lgkmcnt(0)\n\ts_barrier" ::: "memory");

        bc  = (bc == 2)  ? 0 : bc + 1;
        bn2 = (bn2 == 2) ? 0 : bn2 + 1;
    }
}

extern "C" void kernel_launch(void* const* d_in, const int* in_sizes, int n_in,
                              void* d_out, int out_size, void* d_ws, size_t ws_size,
                              hipStream_t stream) {
    const float* feat = (const float*)d_in[0];
    const float* w1   = (const float*)d_in[1];
    const float* w2   = (const float*)d_in[2];
    const float* bias = (const float*)d_in[3];
    const float* v3   = (const float*)d_in[4];
    const float* gk   = (const float*)d_in[5];
    const float* grk  = (const float*)d_in[6];
    const float* gb   = (const float*)d_in[7];
    float* out = (float*)d_out;

    char* wsb = (char*)d_ws;
    float* left  = (float*)(wsb);
    float* right = (float*)(wsb + (size_t)2 * 1024 * 1024);
    float* cbuf  = (float*)(wsb + (size_t)4 * 1024 * 1024);
    float* xp    = (float*)(wsb + (size_t)6 * 1024 * 1024);

    k1_leftright<<<2048 / 8, 256, 0, stream>>>(feat, w1, w2, left, right);
    k2_attn<<<NSEQ * SEQ, 128, 0, stream>>>(feat, left, right, bias, v3, cbuf);
    k3_xproj<<<2048 / 8, 256, 0, stream>>>(feat, cbuf, gk, gb, xp);
    k4_gru<<<NSEQ, 512, 0, stream>>>(grk, gb, xp, out);
}

// Round 9
// 308.983 us; speedup vs baseline: 1.7535x; 1.0389x over previous
//
#include <hip/hip_runtime.h>
#include <hip/hip_bf16.h>

typedef __attribute__((ext_vector_type(8))) short short8;
typedef __attribute__((ext_vector_type(4))) float floatx4;

#define NSEQ 16
#define SEQ 128
#define DIM 256
#define HID 256
#define K3H 768
#define K2D 512
#define LOG2E 1.442695041f
#define LOG2E2 2.885390082f
#define WS_STRIDE 772   // 768 + 4: breaks 16-way preload bank conflict to 2-way (free)

__device__ __forceinline__ float frcp(float x) { return __builtin_amdgcn_rcpf(x); }
__device__ __forceinline__ unsigned short bf16bits(float v) {
    unsigned u = __builtin_bit_cast(unsigned, v);
    unsigned r = (u + 0x7FFFu + ((u >> 16) & 1u)) >> 16;
    return (unsigned short)r;
}
// async global->LDS DMA, 16B/lane: LDS dest = uniform base + lane*16 (HW rule)
__device__ __forceinline__ void load_lds16(const float* gsrc, float* ldsbase) {
    __builtin_amdgcn_global_load_lds(
        (const __attribute__((address_space(1))) void*)gsrc,
        (__attribute__((address_space(3))) void*)ldsbase, 16, 0, 0);
}

// ---------------- K1: left = x@w1, right = x@w2  (8 rows/block) ----------------
// outputs prescaled by 2*log2e so k2's tanh needs no per-element multiply
__global__ __launch_bounds__(256) void k1_leftright(
        const float* __restrict__ x, const float* __restrict__ w1,
        const float* __restrict__ w2, float* __restrict__ left,
        float* __restrict__ right) {
    __shared__ __align__(16) float xs[8][DIM];
    const int tid = threadIdx.x;
    const int r0 = blockIdx.x * 8;
    #pragma unroll
    for (int i = 0; i < 8; ++i) xs[i][tid] = x[(r0 + i) * DIM + tid];
    __syncthreads();
    float accL[8], accR[8];
    #pragma unroll
    for (int i = 0; i < 8; ++i) { accL[i] = 0.f; accR[i] = 0.f; }
    #pragma unroll 4
    for (int d = 0; d < DIM; ++d) {
        float wa = w1[d * DIM + tid];
        float wb = w2[d * DIM + tid];
        #pragma unroll
        for (int i = 0; i < 8; ++i) {
            float xv = xs[i][d];
            accL[i] = fmaf(xv, wa, accL[i]);
            accR[i] = fmaf(xv, wb, accR[i]);
        }
    }
    #pragma unroll
    for (int i = 0; i < 8; ++i) {
        left[(r0 + i) * DIM + tid]  = accL[i] * LOG2E2;
        right[(r0 + i) * DIM + tid] = accR[i] * LOG2E2;
    }
}

// ---------------- K2: scores (tanh, v3 dot), softmax, c = score@x ----------------
// left/right arrive prescaled by 2log2e: tanh(t) = 1 - 2/(1+exp2(t'))
__global__ __launch_bounds__(128) void k2_attn(
        const float* __restrict__ x, const float* __restrict__ left,
        const float* __restrict__ right, const float* __restrict__ bias,
        const float* __restrict__ v3, float* __restrict__ cout) {
    __shared__ __align__(16) float lm[DIM];
    __shared__ __align__(16) float v3s[DIM];
    __shared__ float p[SEQ];
    __shared__ float red[2];
    const int tid = threadIdx.x;      // 0..127 (= n)
    const int lane = tid & 63;
    const int wid = tid >> 6;         // 0..1
    const int bm = blockIdx.x;        // 0..2047
    const int b = bm >> 7;            // sequence index

    const float* lrow = left + bm * DIM;
    #pragma unroll
    for (int q = 0; q < 2; ++q) {
        int d = tid + q * 128;
        lm[d]  = lrow[d] + bias[d] * LOG2E2;   // bias scaled to match k1 prescale
        v3s[d] = v3[d];
    }
    __syncthreads();

    const float4* rrow = reinterpret_cast<const float4*>(right + (b * SEQ + tid) * DIM);
    const float4* lm4  = reinterpret_cast<const float4*>(lm);
    const float4* vv4  = reinterpret_cast<const float4*>(v3s);
    float s = 0.f;
    for (int d4 = 0; d4 < DIM / 4; ++d4) {
        float4 rv = rrow[d4];
        float4 lv = lm4[d4];
        float4 vv = vv4[d4];
        float t0 = 1.f - 2.f * frcp(1.f + __builtin_amdgcn_exp2f(lv.x + rv.x));
        float t1 = 1.f - 2.f * frcp(1.f + __builtin_amdgcn_exp2f(lv.y + rv.y));
        float t2 = 1.f - 2.f * frcp(1.f + __builtin_amdgcn_exp2f(lv.z + rv.z));
        float t3 = 1.f - 2.f * frcp(1.f + __builtin_amdgcn_exp2f(lv.w + rv.w));
        s = fmaf(t0, vv.x, s);
        s = fmaf(t1, vv.y, s);
        s = fmaf(t2, vv.z, s);
        s = fmaf(t3, vv.w, s);
    }
    float m = s;
    #pragma unroll
    for (int off = 32; off >= 1; off >>= 1) m = fmaxf(m, __shfl_xor(m, off, 64));
    if (lane == 0) red[wid] = m;
    __syncthreads();
    m = fmaxf(red[0], red[1]);
    float e = __expf(s - m);
    float t = e;
    #pragma unroll
    for (int off = 32; off >= 1; off >>= 1) t += __shfl_xor(t, off, 64);
    __syncthreads();
    if (lane == 0) red[wid] = t;
    __syncthreads();
    float denom = red[0] + red[1];
    p[tid] = e * frcp(denom);
    __syncthreads();

    const float* xb = x + b * SEQ * DIM;
    float c0 = 0.f, c1 = 0.f;
    #pragma unroll 4
    for (int n = 0; n < SEQ; ++n) {
        float pn = p[n];
        c0 = fmaf(pn, xb[n * DIM + tid], c0);
        c1 = fmaf(pn, xb[n * DIM + tid + 128], c1);
    }
    cout[bm * DIM + tid]       = c0;
    cout[bm * DIM + tid + 128] = c1;
}

// ---------------- K3: xp = [x,c]@gru_kernel + biases, prescaled (v8-proven) ----------------
// z,r streams carry (b_in + b_rec)*log2e; h stream carries b_in*2log2e only
// (b_rec_h multiplies r in the GRU, handled per-lane in k4).
__global__ __launch_bounds__(256) void k3_xproj(
        const float* __restrict__ x, const float* __restrict__ c,
        const float* __restrict__ gk, const float* __restrict__ gbias,
        float* __restrict__ xp) {
    __shared__ __align__(16) float xc[8][K2D];
    const int tid = threadIdx.x;
    const int r0 = blockIdx.x * 8;
    #pragma unroll
    for (int i = 0; i < 8; ++i) {
        xc[i][tid]       = x[(r0 + i) * DIM + tid];
        xc[i][tid + 256] = c[(r0 + i) * DIM + tid];
    }
    __syncthreads();
    const float bz = gbias[tid]       + gbias[K3H + tid];
    const float br = gbias[256 + tid] + gbias[K3H + 256 + tid];
    const float bh = gbias[512 + tid];
    float acc[8][3];
    #pragma unroll
    for (int i = 0; i < 8; ++i) {
        acc[i][0] = bz;
        acc[i][1] = br;
        acc[i][2] = bh;
    }
    #pragma unroll 2
    for (int k = 0; k < K2D; ++k) {
        float g0 = gk[k * K3H + tid];
        float g1 = gk[k * K3H + 256 + tid];
        float g2 = gk[k * K3H + 512 + tid];
        #pragma unroll
        for (int i = 0; i < 8; ++i) {
            float xv = xc[i][k];
            acc[i][0] = fmaf(xv, g0, acc[i][0]);
            acc[i][1] = fmaf(xv, g1, acc[i][1]);
            acc[i][2] = fmaf(xv, g2, acc[i][2]);
        }
    }
    #pragma unroll
    for (int i = 0; i < 8; ++i) {
        xp[(r0 + i) * K3H + tid]       = acc[i][0] * LOG2E;
        xp[(r0 + i) * K3H + 256 + tid] = acc[i][1] * LOG2E;
        xp[(r0 + i) * K3H + 512 + tid] = acc[i][2] * LOG2E2;
    }
}

// ---------------- K4: GRU recurrence v9 = v8 + critical-path trims ----------------
// vs v8 (all v8 structure kept: 1 barrier/step, in-register gates, DMA dist-2,
// unmasked broadcast A, no spill):
//  (1) A-frags + xq gate inputs read UNCONDITIONALLY before the MFMA loop (no
//      exec-region trap; xq latency hides under the 466-cyc MFMA phase).
//  (2) gates spread over lanes 0-31, ONE column each (valid because broadcast-A
//      makes every C row equal rp): 6 trans-ops/wave instead of 12, single
//      hbf write + out store per lane; b_rec_h now a per-lane register.
//  (3) RACE FIX: DMA always issued (tail rows clamp to SEQ-1 into a never-read
//      buffer) so outstanding-count is constant; barrier waits exactly vmcnt(3)
//      (= st, DMA, st issued after the DMA consumed next step).
__global__ __launch_bounds__(512) void k4_gru(
        const float* __restrict__ rec, const float* __restrict__ gbias,
        const float* __restrict__ xp, float* __restrict__ out) {
    __shared__ __align__(16) float ws[16 * WS_STRIDE];    // 49.4KB preload staging
    __shared__ __align__(16) float xq[3][K3H];            // 9KB triple-buffered gate inputs
    __shared__ __align__(16) unsigned short hbf[2][HID];  // 1KB dbuf h (bf16)
    const int tid  = threadIdx.x;
    const int lane = tid & 63;
    const int wv   = tid >> 6;     // 0..7
    const int seq  = blockIdx.x;   // 0..15
    const int l15  = lane & 15;
    const int g4   = lane >> 4;    // 0..3

    // ---- Preload rec_kernel as prescaled bf16 B-fragments (v8 mapping) ----
    short8 Bf[6][8];
    #pragma unroll
    for (int part = 0; part < 16; ++part) {
        #pragma unroll
        for (int q = 0; q < 6; ++q) {
            int fi = q * 512 + tid;            // 3072 float4 = 16 rows x 192 float4
            int row = fi / 192, c4 = fi % 192;
            reinterpret_cast<float4*>(ws)[row * (WS_STRIDE / 4) + c4] =
                reinterpret_cast<const float4*>(rec + part * 16 * K3H)[fi];
        }
        __syncthreads();
        const int kc = part >> 1, half = part & 1;
        #pragma unroll
        for (int u = 0; u < 6; ++u) {
            const float sc = (u >= 4) ? LOG2E2 : LOG2E;
            const int col = (u >> 1) * 256 + (u & 1) * 16 + wv * 32 + l15;
            #pragma unroll
            for (int j = 0; j < 8; ++j) {
                int r = g4 * 8 + j;            // k within 32-chunk
                if ((r >> 4) == half)
                    Bf[u][kc][j] = (short)bf16bits(ws[(r & 15) * WS_STRIDE + col] * sc);
            }
        }
        __syncthreads();
    }

    // gate-lane column (lanes 0-31 active; 32-63 mirror for broadcast reads)
    const int dd = wv * 32 + (lane & 31);
    const float brh_l = gbias[K3H + 512 + dd] * LOG2E2;   // b_rec_h, per-lane reg
    const int tsel = (lane >> 4) & 1;                      // 0: u even, 1: u odd

    const float* xps = xp + (size_t)seq * SEQ * K3H;
    float* outs = out + (size_t)seq * SEQ * HID;

    float h = 0.f;
    if (tid < HID) hbf[0][tid] = 0;

    // prologue: DMA rows 0 and 1 into xq[0], xq[1]; full drain once
    if (wv < 3) {
        load_lds16(xps + wv * 256 + (lane << 2),       &xq[0][wv * 256]);
        load_lds16(xps + K3H + wv * 256 + (lane << 2), &xq[1][wv * 256]);
    }
    asm volatile("s_waitcnt vmcnt(0)" ::: "memory");
    __syncthreads();

    int bc = 0, bn2 = 2;            // xq buffer for step s, and for s+2
    for (int s = 0; s < SEQ; ++s) {
        const int cb = s & 1, nb = cb ^ 1;

        // (A) DMA prefetch — ALWAYS issued (tail clamps; keeps vmcnt count exact)
        const int sp = (s + 2 < SEQ) ? s + 2 : SEQ - 1;
        if (wv < 3)
            load_lds16(xps + (size_t)sp * K3H + wv * 256 + (lane << 2), &xq[bn2][wv * 256]);

        // (B) A-fragments upfront (broadcast, conflict-free), then xq gate inputs
        //     (unconditional: all issued before MFMAs, latency hidden under them)
        short8 av[8];
        #pragma unroll
        for (int kc = 0; kc < 8; ++kc)
            av[kc] = *reinterpret_cast<const short8*>(&hbf[cb][kc * 32 + g4 * 8]);
        const float xz = xq[bc][dd];
        const float xr = xq[bc][256 + dd];
        const float xh = xq[bc][512 + dd];

        // (C) rp = h @ rec (M=1, A rows broadcast-equal), biases folded upstream
        floatx4 C[6];
        #pragma unroll
        for (int u = 0; u < 6; ++u) C[u] = (floatx4){0.f, 0.f, 0.f, 0.f};
        #pragma unroll
        for (int kc = 0; kc < 8; ++kc) {
            #pragma unroll
            for (int u = 0; u < 6; ++u)
                C[u] = __builtin_amdgcn_mfma_f32_16x16x32_bf16(av[kc], Bf[u][kc], C[u], 0, 0, 0);
        }
        // (D) gates: lanes 0-31, one column each (all C rows equal rp)
        if (lane < 32) {
            float rz = tsel ? C[1][0] : C[0][0];
            float rr = tsel ? C[3][0] : C[2][0];
            float rh = tsel ? C[5][0] : C[4][0];
            float z  = frcp(1.f + __builtin_amdgcn_exp2f(-(rz + xz)));
            float r  = frcp(1.f + __builtin_amdgcn_exp2f(-(rr + xr)));
            float th = fmaf(r, rh + brh_l, xh);
            float hh = 1.f - 2.f * frcp(1.f + __builtin_amdgcn_exp2f(th));
            h = hh + z * (h - hh);
            hbf[nb][dd] = bf16bits(h);
            outs[s * HID + dd] = h;
        }
        // single barrier: LDS drained; DMA/stores stay in flight (counted vmcnt)
        asm volatile("s_waitcnt vmcnt(3) lgkmcnt(0)\n\ts_barrier" ::: "memory");

        bc  = (bc == 2)  ? 0 : bc + 1;
        bn2 = (bn2 == 2) ? 0 : bn2 + 1;
    }
}

extern "C" void kernel_launch(void* const* d_in, const int* in_sizes, int n_in,
                              void* d_out, int out_size, void* d_ws, size_t ws_size,
                              hipStream_t stream) {
    const float* feat = (const float*)d_in[0];
    const float* w1   = (const float*)d_in[1];
    const float* w2   = (const float*)d_in[2];
    const float* bias = (const float*)d_in[3];
    const float* v3   = (const float*)d_in[4];
    const float* gk   = (const float*)d_in[5];
    const float* grk  = (const float*)d_in[6];
    const float* gb   = (const float*)d_in[7];
    float* out = (float*)d_out;

    char* wsb = (char*)d_ws;
    float* left  = (float*)(wsb);
    float* right = (float*)(wsb + (size_t)2 * 1024 * 1024);
    float* cbuf  = (float*)(wsb + (size_t)4 * 1024 * 1024);
    float* xp    = (float*)(wsb + (size_t)6 * 1024 * 1024);

    k1_leftright<<<2048 / 8, 256, 0, stream>>>(feat, w1, w2, left, right);
    k2_attn<<<NSEQ * SEQ, 128, 0, stream>>>(feat, left, right, bias, v3, cbuf);
    k3_xproj<<<2048 / 8, 256, 0, stream>>>(feat, cbuf, gk, gb, xp);
    k4_gru<<<NSEQ, 512, 0, stream>>>(grk, gb, xp, out);
}

// Round 10
// 241.865 us; speedup vs baseline: 2.2401x; 1.2775x over previous
//
#include <hip/hip_runtime.h>
#include <hip/hip_bf16.h>

typedef __attribute__((ext_vector_type(8))) short short8;
typedef __attribute__((ext_vector_type(4))) float floatx4;

#define NSEQ 16
#define SEQ 128
#define DIM 256
#define HID 256
#define K3H 768
#define K2D 512
#define LOG2E 1.442695041f
#define LOG2E2 2.885390082f
#define WS_STRIDE 772   // 768 + 4: breaks 16-way preload bank conflict to 2-way (free)

__device__ __forceinline__ float frcp(float x) { return __builtin_amdgcn_rcpf(x); }
__device__ __forceinline__ unsigned short bf16bits(float v) {
    unsigned u = __builtin_bit_cast(unsigned, v);
    unsigned r = (u + 0x7FFFu + ((u >> 16) & 1u)) >> 16;
    return (unsigned short)r;
}
// async global->LDS DMA, 16B/lane: LDS dest = uniform base + lane*16 (HW rule)
__device__ __forceinline__ void load_lds16(const float* gsrc, float* ldsbase) {
    __builtin_amdgcn_global_load_lds(
        (const __attribute__((address_space(1))) void*)gsrc,
        (__attribute__((address_space(3))) void*)ldsbase, 16, 0, 0);
}

// ---------------- K1: left = x@w1, right = x@w2  (8 rows/block, v1-proven) ----------------
// outputs prescaled by 2*log2e (k2 consumes via exp2-tanh)
__global__ __launch_bounds__(256) void k1_leftright(
        const float* __restrict__ x, const float* __restrict__ w1,
        const float* __restrict__ w2, float* __restrict__ left,
        float* __restrict__ right) {
    __shared__ __align__(16) float xs[8][DIM];
    const int tid = threadIdx.x;
    const int r0 = blockIdx.x * 8;
    #pragma unroll
    for (int i = 0; i < 8; ++i) xs[i][tid] = x[(r0 + i) * DIM + tid];
    __syncthreads();
    float accL[8], accR[8];
    #pragma unroll
    for (int i = 0; i < 8; ++i) { accL[i] = 0.f; accR[i] = 0.f; }
    #pragma unroll 4
    for (int d = 0; d < DIM; ++d) {
        float wa = w1[d * DIM + tid];
        float wb = w2[d * DIM + tid];
        #pragma unroll
        for (int i = 0; i < 8; ++i) {
            float xv = xs[i][d];
            accL[i] = fmaf(xv, wa, accL[i]);
            accR[i] = fmaf(xv, wb, accR[i]);
        }
    }
    #pragma unroll
    for (int i = 0; i < 8; ++i) {
        left[(r0 + i) * DIM + tid]  = accL[i] * LOG2E2;
        right[(r0 + i) * DIM + tid] = accR[i] * LOG2E2;
    }
}

// ---------------- K2 v2: 8 m-rows per block ----------------
// grid 256 = (b 0..15) x (mt 0..15); 256 threads. right[b] read once per 8 rows
// (8x less re-streaming). Scores: thread (mi=tid>>5, nl=tid&31) does 4 dots (ILP).
// Softmax: wave-local, xor-shuffle within 32-lane groups. c: thread-per-d, P via b128.
__global__ __launch_bounds__(256) void k2_attn(
        const float* __restrict__ x, const float* __restrict__ left,
        const float* __restrict__ right, const float* __restrict__ bias,
        const float* __restrict__ v3, float* __restrict__ cout) {
    __shared__ __align__(16) float lm[8][DIM];
    __shared__ __align__(16) float v3s[DIM];
    __shared__ __align__(16) float P[8][SEQ];
    const int tid = threadIdx.x;
    const int b  = blockIdx.x >> 4;          // sequence
    const int m0 = (blockIdx.x & 15) * 8;    // first of 8 m-rows

    v3s[tid & 255] = v3[tid & 255];
    #pragma unroll
    for (int i = 0; i < 8; ++i)
        lm[i][tid] = left[(size_t)(b * SEQ + m0 + i) * DIM + tid] + bias[tid] * LOG2E2;
    __syncthreads();

    // ---- scores ----
    const int mi = tid >> 5;        // 0..7
    const int nl = tid & 31;        // 0..31
    float sacc[4] = {0.f, 0.f, 0.f, 0.f};
    const float4* lv4 = reinterpret_cast<const float4*>(lm[mi]);
    const float4* vv4 = reinterpret_cast<const float4*>(v3s);
    #pragma unroll 2
    for (int d4 = 0; d4 < DIM / 4; ++d4) {
        float4 lv = lv4[d4];
        float4 vv = vv4[d4];
        #pragma unroll
        for (int rep = 0; rep < 4; ++rep) {
            const int n = nl + rep * 32;
            float4 rv = reinterpret_cast<const float4*>(right + (size_t)(b * SEQ + n) * DIM)[d4];
            float t0 = 1.f - 2.f * frcp(1.f + __builtin_amdgcn_exp2f(lv.x + rv.x));
            float t1 = 1.f - 2.f * frcp(1.f + __builtin_amdgcn_exp2f(lv.y + rv.y));
            float t2 = 1.f - 2.f * frcp(1.f + __builtin_amdgcn_exp2f(lv.z + rv.z));
            float t3 = 1.f - 2.f * frcp(1.f + __builtin_amdgcn_exp2f(lv.w + rv.w));
            sacc[rep] = fmaf(t0, vv.x, sacc[rep]);
            sacc[rep] = fmaf(t1, vv.y, sacc[rep]);
            sacc[rep] = fmaf(t2, vv.z, sacc[rep]);
            sacc[rep] = fmaf(t3, vv.w, sacc[rep]);
        }
    }
    #pragma unroll
    for (int rep = 0; rep < 4; ++rep) P[mi][nl + rep * 32] = sacc[rep];
    __syncthreads();

    // ---- softmax: wave w handles rows w*2 + (lane>>5); 32 lanes per row ----
    {
        const int w   = tid >> 6;
        const int lane = tid & 63;
        const int row = w * 2 + (lane >> 5);
        const int g   = lane & 31;
        float v0 = P[row][g], v1 = P[row][g + 32], v2 = P[row][g + 64], v3v = P[row][g + 96];
        float mx = fmaxf(fmaxf(v0, v1), fmaxf(v2, v3v));
        #pragma unroll
        for (int off = 16; off >= 1; off >>= 1) mx = fmaxf(mx, __shfl_xor(mx, off, 64));
        float e0 = __expf(v0 - mx), e1 = __expf(v1 - mx);
        float e2 = __expf(v2 - mx), e3 = __expf(v3v - mx);
        float sm = e0 + e1 + e2 + e3;
        #pragma unroll
        for (int off = 16; off >= 1; off >>= 1) sm += __shfl_xor(sm, off, 64);
        float inv = frcp(sm);
        P[row][g] = e0 * inv; P[row][g + 32] = e1 * inv;
        P[row][g + 64] = e2 * inv; P[row][g + 96] = e3 * inv;
    }
    __syncthreads();

    // ---- c[m0+i][d] = sum_n P[i][n] x[b,n,d]; thread = d ----
    float acc[8];
    #pragma unroll
    for (int i = 0; i < 8; ++i) acc[i] = 0.f;
    const float* xb = x + (size_t)b * SEQ * DIM;
    for (int nc = 0; nc < SEQ / 4; ++nc) {
        float xv0 = xb[(nc * 4 + 0) * DIM + tid];
        float xv1 = xb[(nc * 4 + 1) * DIM + tid];
        float xv2 = xb[(nc * 4 + 2) * DIM + tid];
        float xv3 = xb[(nc * 4 + 3) * DIM + tid];
        #pragma unroll
        for (int i = 0; i < 8; ++i) {
            float4 pv = *reinterpret_cast<const float4*>(&P[i][nc * 4]);
            acc[i] = fmaf(pv.x, xv0, acc[i]);
            acc[i] = fmaf(pv.y, xv1, acc[i]);
            acc[i] = fmaf(pv.z, xv2, acc[i]);
            acc[i] = fmaf(pv.w, xv3, acc[i]);
        }
    }
    #pragma unroll
    for (int i = 0; i < 8; ++i)
        cout[(size_t)(b * SEQ + m0 + i) * DIM + tid] = acc[i];
}

// ---------------- K3 v2: bf16 MFMA GEMM  xp = [x|c] @ gk (+bias, prescaled) ----------------
// M=2048 N=768 K=512. 128 blocks (32 m-tiles x 4 n-tiles), 512 thr. Block tile
// 64m x 192n; wave (wm=w>>2, wn=w&3) tile 32m x 48n = 2x3 frags; KC=64, 8 chunks,
// single-buffered. Bs stored TRANSPOSED [n][k] so B-frags read as contiguous b128.
// +8-ushort row pad -> 2-way bank conflicts. Biases folded + log2e prescale in epilogue.
__global__ __launch_bounds__(512) void k3_mfma(
        const float* __restrict__ x, const float* __restrict__ c,
        const float* __restrict__ gk, const float* __restrict__ gbias,
        float* __restrict__ xp) {
    __shared__ __align__(16) unsigned short As[64][72];    // [m][k]
    __shared__ __align__(16) unsigned short Bs[192][72];   // [n][k] (transposed)
    const int tid  = threadIdx.x;
    const int lane = tid & 63;
    const int w    = tid >> 6;
    const int l15  = lane & 15;
    const int g4   = lane >> 4;
    const int wm   = w >> 2;          // 0..1
    const int wn   = w & 3;           // 0..3
    const int m0   = (blockIdx.x & 31) * 64;
    const int n0   = (blockIdx.x >> 5) * 192;

    floatx4 Cf[2][3];
    #pragma unroll
    for (int i = 0; i < 2; ++i)
        #pragma unroll
        for (int j = 0; j < 3; ++j) Cf[i][j] = (floatx4){0.f, 0.f, 0.f, 0.f};

    for (int ch = 0; ch < 8; ++ch) {
        // stage A chunk: 64m x 64k fp32 -> bf16  (1024 float4)
        const int kbase = ch * 64;
        #pragma unroll
        for (int q = 0; q < 2; ++q) {
            int fi = q * 512 + tid;
            int row = fi >> 4, kq = (fi & 15) << 2;
            int kg = kbase + kq;
            const float* src = (kg < 256) ? &x[(size_t)(m0 + row) * DIM + kg]
                                          : &c[(size_t)(m0 + row) * DIM + (kg - 256)];
            float4 v = *reinterpret_cast<const float4*>(src);
            unsigned short* dst = &As[row][kq];
            dst[0] = bf16bits(v.x); dst[1] = bf16bits(v.y);
            dst[2] = bf16bits(v.z); dst[3] = bf16bits(v.w);
        }
        // stage B chunk: 64k x 192n fp32 -> bf16, TRANSPOSED into Bs[n][k] (3072 float4)
        #pragma unroll
        for (int q = 0; q < 6; ++q) {
            int fi = q * 512 + tid;
            int krow = fi / 48, nq = (fi % 48) << 2;
            float4 v = *reinterpret_cast<const float4*>(
                &gk[(size_t)(kbase + krow) * K3H + n0 + nq]);
            Bs[nq + 0][krow] = bf16bits(v.x);
            Bs[nq + 1][krow] = bf16bits(v.y);
            Bs[nq + 2][krow] = bf16bits(v.z);
            Bs[nq + 3][krow] = bf16bits(v.w);
        }
        __syncthreads();
        #pragma unroll
        for (int kk = 0; kk < 2; ++kk) {
            short8 af[2], bf[3];
            #pragma unroll
            for (int i = 0; i < 2; ++i)
                af[i] = *reinterpret_cast<const short8*>(&As[wm * 32 + i * 16 + l15][kk * 32 + g4 * 8]);
            #pragma unroll
            for (int j = 0; j < 3; ++j)
                bf[j] = *reinterpret_cast<const short8*>(&Bs[wn * 48 + j * 16 + l15][kk * 32 + g4 * 8]);
            #pragma unroll
            for (int i = 0; i < 2; ++i)
                #pragma unroll
                for (int j = 0; j < 3; ++j)
                    Cf[i][j] = __builtin_amdgcn_mfma_f32_16x16x32_bf16(af[i], bf[j], Cf[i][j], 0, 0, 0);
        }
        __syncthreads();
    }

    // epilogue: xp[r][col] = acc*sc + bias*sc  (sc,bias frag-uniform per n-region)
    #pragma unroll
    for (int j = 0; j < 3; ++j) {
        const int nbase = n0 + wn * 48 + j * 16;
        const int col = nbase + l15;
        const float sc = (nbase >= 512) ? LOG2E2 : LOG2E;
        const float bv = ((col < 512) ? (gbias[col] + gbias[K3H + col]) : gbias[col]) * sc;
        #pragma unroll
        for (int i = 0; i < 2; ++i) {
            const int rbase = m0 + wm * 32 + i * 16 + g4 * 4;
            #pragma unroll
            for (int r = 0; r < 4; ++r)
                xp[(size_t)(rbase + r) * K3H + col] = fmaf(Cf[i][j][r], sc, bv);
        }
    }
}

// ---------------- K4: GRU recurrence v9 (unchanged, proven 181us) ----------------
__global__ __launch_bounds__(512) void k4_gru(
        const float* __restrict__ rec, const float* __restrict__ gbias,
        const float* __restrict__ xp, float* __restrict__ out) {
    __shared__ __align__(16) float ws[16 * WS_STRIDE];    // 49.4KB preload staging
    __shared__ __align__(16) float xq[3][K3H];            // 9KB triple-buffered gate inputs
    __shared__ __align__(16) unsigned short hbf[2][HID];  // 1KB dbuf h (bf16)
    const int tid  = threadIdx.x;
    const int lane = tid & 63;
    const int wv   = tid >> 6;     // 0..7
    const int seq  = blockIdx.x;   // 0..15
    const int l15  = lane & 15;
    const int g4   = lane >> 4;    // 0..3

    short8 Bf[6][8];
    #pragma unroll
    for (int part = 0; part < 16; ++part) {
        #pragma unroll
        for (int q = 0; q < 6; ++q) {
            int fi = q * 512 + tid;
            int row = fi / 192, c4 = fi % 192;
            reinterpret_cast<float4*>(ws)[row * (WS_STRIDE / 4) + c4] =
                reinterpret_cast<const float4*>(rec + part * 16 * K3H)[fi];
        }
        __syncthreads();
        const int kc = part >> 1, half = part & 1;
        #pragma unroll
        for (int u = 0; u < 6; ++u) {
            const float sc = (u >= 4) ? LOG2E2 : LOG2E;
            const int col = (u >> 1) * 256 + (u & 1) * 16 + wv * 32 + l15;
            #pragma unroll
            for (int j = 0; j < 8; ++j) {
                int r = g4 * 8 + j;
                if ((r >> 4) == half)
                    Bf[u][kc][j] = (short)bf16bits(ws[(r & 15) * WS_STRIDE + col] * sc);
            }
        }
        __syncthreads();
    }

    const int dd = wv * 32 + (lane & 31);
    const float brh_l = gbias[K3H + 512 + dd] * LOG2E2;
    const int tsel = (lane >> 4) & 1;

    const float* xps = xp + (size_t)seq * SEQ * K3H;
    float* outs = out + (size_t)seq * SEQ * HID;

    float h = 0.f;
    if (tid < HID) hbf[0][tid] = 0;

    if (wv < 3) {
        load_lds16(xps + wv * 256 + (lane << 2),       &xq[0][wv * 256]);
        load_lds16(xps + K3H + wv * 256 + (lane << 2), &xq[1][wv * 256]);
    }
    asm volatile("s_waitcnt vmcnt(0)" ::: "memory");
    __syncthreads();

    int bc = 0, bn2 = 2;
    for (int s = 0; s < SEQ; ++s) {
        const int cb = s & 1, nb = cb ^ 1;

        const int sp = (s + 2 < SEQ) ? s + 2 : SEQ - 1;
        if (wv < 3)
            load_lds16(xps + (size_t)sp * K3H + wv * 256 + (lane << 2), &xq[bn2][wv * 256]);

        short8 av[8];
        #pragma unroll
        for (int kc = 0; kc < 8; ++kc)
            av[kc] = *reinterpret_cast<const short8*>(&hbf[cb][kc * 32 + g4 * 8]);
        const float xz = xq[bc][dd];
        const float xr = xq[bc][256 + dd];
        const float xh = xq[bc][512 + dd];

        floatx4 C[6];
        #pragma unroll
        for (int u = 0; u < 6; ++u) C[u] = (floatx4){0.f, 0.f, 0.f, 0.f};
        #pragma unroll
        for (int kc = 0; kc < 8; ++kc) {
            #pragma unroll
            for (int u = 0; u < 6; ++u)
                C[u] = __builtin_amdgcn_mfma_f32_16x16x32_bf16(av[kc], Bf[u][kc], C[u], 0, 0, 0);
        }
        if (lane < 32) {
            float rz = tsel ? C[1][0] : C[0][0];
            float rr = tsel ? C[3][0] : C[2][0];
            float rh = tsel ? C[5][0] : C[4][0];
            float z  = frcp(1.f + __builtin_amdgcn_exp2f(-(rz + xz)));
            float r  = frcp(1.f + __builtin_amdgcn_exp2f(-(rr + xr)));
            float th = fmaf(r, rh + brh_l, xh);
            float hh = 1.f - 2.f * frcp(1.f + __builtin_amdgcn_exp2f(th));
            h = hh + z * (h - hh);
            hbf[nb][dd] = bf16bits(h);
            outs[s * HID + dd] = h;
        }
        asm volatile("s_waitcnt vmcnt(3) lgkmcnt(0)\n\ts_barrier" ::: "memory");

        bc  = (bc == 2)  ? 0 : bc + 1;
        bn2 = (bn2 == 2) ? 0 : bn2 + 1;
    }
}

extern "C" void kernel_launch(void* const* d_in, const int* in_sizes, int n_in,
                              void* d_out, int out_size, void* d_ws, size_t ws_size,
                              hipStream_t stream) {
    const float* feat = (const float*)d_in[0];
    const float* w1   = (const float*)d_in[1];
    const float* w2   = (const float*)d_in[2];
    const float* bias = (const float*)d_in[3];
    const float* v3   = (const float*)d_in[4];
    const float* gk   = (const float*)d_in[5];
    const float* grk  = (const float*)d_in[6];
    const float* gb   = (const float*)d_in[7];
    float* out = (float*)d_out;

    char* wsb = (char*)d_ws;
    float* left  = (float*)(wsb);
    float* right = (float*)(wsb + (size_t)2 * 1024 * 1024);
    float* cbuf  = (float*)(wsb + (size_t)4 * 1024 * 1024);
    float* xp    = (float*)(wsb + (size_t)6 * 1024 * 1024);

    k1_leftright<<<2048 / 8, 256, 0, stream>>>(feat, w1, w2, left, right);
    k2_attn<<<NSEQ * 16, 256, 0, stream>>>(feat, left, right, bias, v3, cbuf);
    k3_mfma<<<128, 512, 0, stream>>>(feat, cbuf, gk, gb, xp);
    k4_gru<<<NSEQ, 512, 0, stream>>>(grk, gb, xp, out);
}